// Round 5
// baseline (105.321 us; speedup 1.0000x reference)
//
#include <hip/hip_runtime.h>
#include <hip/hip_bf16.h>
#include <math.h>

// Problem: B=8192, D=1024, H=128, C=16
// out tuple: masked[B*D], mask_norm(0.0), embed_norm(||x||F), x[B*D]  -> f32
#define B_ 8192
#define D_ 1024
#define H_ 128
#define C_ 16
#define BD (B_*D_)
#define STM 32              // subtile rows (one block processes one subtile)
#define SLOTS 64            // block-slots per XCD (grid = 8*SLOTS)
#define MAXSUB 336          // max subtiles per XCD (worst-case skew: 258)

using bf16x8 = __attribute__((ext_vector_type(8))) __bf16;
using f32x4  = __attribute__((ext_vector_type(4))) float;
typedef unsigned short ushort_t;

// ws layout:
//   int idx 16..23   : nsub[8]            (byte 64)
//   int idx 32..8095 : subtbl[8][336][3]  (cond,row0,end)
//   int idx 8192..   : sidx[8192]         (byte 32768)
//   byte 65536       : psum[8192*2] f32   (64 KiB)
//   byte 131072      : ep[16] f32

__device__ inline bf16x8 cvt8(float4 a, float4 b) {
    bf16x8 r;
    r[0] = (__bf16)a.x; r[1] = (__bf16)a.y; r[2] = (__bf16)a.z; r[3] = (__bf16)a.w;
    r[4] = (__bf16)b.x; r[5] = (__bf16)b.y; r[6] = (__bf16)b.z; r[7] = (__bf16)b.w;
    return r;
}

// ---- fused histogram + per-XCD subtile table + scatter; zeroes ep ----
__global__ __launch_bounds__(1024) void k_sort(const int* __restrict__ c,
                                               int* __restrict__ w,
                                               float* __restrict__ ep) {
    __shared__ int hist[C_], base[C_];
    int tid = threadIdx.x;
    if (tid < C_) { hist[tid] = 0; ep[tid] = 0.0f; }
    __syncthreads();
    int myc[8];
#pragma unroll
    for (int i = 0; i < 8; ++i) {
        myc[i] = c[tid * 8 + i];
        atomicAdd(&hist[myc[i]], 1);
    }
    __syncthreads();
    if (tid == 0) {
        int off = 0; int ns[8] = {0,0,0,0,0,0,0,0};
        for (int cc = 0; cc < C_; ++cc) {
            int cnt = hist[cc]; base[cc] = off;
            int xcd = cc >> 1;                       // 2 conds per XCD -> 1 MB weights in its L2
            for (int t = 0; t < cnt; t += STM) {
                int s = ns[xcd]++;
                int* e = &w[32 + (xcd * MAXSUB + s) * 3];
                e[0] = cc; e[1] = off + t; e[2] = off + cnt;
            }
            off += cnt;
        }
        for (int xx = 0; xx < 8; ++xx) w[16 + xx] = ns[xx];
    }
    __syncthreads();
#pragma unroll
    for (int i = 0; i < 8; ++i) {
        int pos = atomicAdd(&base[myc[i]], 1);
        w[8192 + pos] = tid * 8 + i;
    }
}

// ---- fused 2-layer MLP per 32-row subtile ----
__global__ __launch_bounds__(256) void k_f(const float* __restrict__ x,
                                           const float* __restrict__ W1,
                                           const float* __restrict__ b1,
                                           const float* __restrict__ W2,
                                           const float* __restrict__ b2,
                                           const int* __restrict__ wsi,
                                           float* __restrict__ psum,
                                           float* __restrict__ out,
                                           float* __restrict__ ep) {
    int xcd = blockIdx.x & 7, slot0 = blockIdx.x >> 3;
    int nsub = wsi[16 + xcd];
    const int* sidx = wsi + 8192;

    __shared__ ushort_t As[STM * 32];     // 2 KB   x slab (bf16, swizzled)
    __shared__ ushort_t Bs[H_ * 32];      // 8 KB   W1 slab
    __shared__ ushort_t Hs[STM * H_];     // 8 KB   h tile (bf16, swizzled)
    __shared__ ushort_t Ws[64 * H_];      // 16 KB  W2 chunk
    __shared__ float red[4];

    int tid = threadIdx.x;
    int wv = tid >> 6, lane = tid & 63, l15 = lane & 15, kg = lane >> 4;
    int rf = wv & 1, cf = wv >> 1;        // row-frag (2x16 rows), col-frag
    float xsq = 0.0f;

    for (int si = slot0; si < nsub; si += SLOTS) {
        const int* e = wsi + 32 + (xcd * MAXSUB + si) * 3;
        int cond = e[0], row0 = e[1], end = e[2];

        // ======== layer 1: h[32][128] = x_tile @ W1^T ========
        bool isx = (tid < 128);                     // waves 0,1 stage x (wave-uniform)
        int ar = (tid >> 2) & 31, aslot = tid & 3;
        int p = row0 + ar;
        bool valid = isx && (p < end);
        int srow = sidx[valid ? p : (end - 1)];
        const float* xrow = x + (size_t)srow * D_ + aslot * 8;
        float* xcopy = out + (size_t)BD + 2 + (size_t)srow * D_ + aslot * 8;
        ushort_t* awr = As + ar * 32 + ((aslot ^ (ar & 3)) * 8);
        int br = tid >> 1, bhalf = tid & 1;
        const float* wrow = W1 + ((size_t)(cond * H_ + br)) * D_ + bhalf * 16;
        ushort_t* bwr0 = Bs + br * 32 + (((bhalf * 2    ) ^ (br & 3)) * 8);
        ushort_t* bwr1 = Bs + br * 32 + (((bhalf * 2 + 1) ^ (br & 3)) * 8);
        int arow = rf * 16 + l15;
        const ushort_t* ard = As + arow * 32 + ((kg ^ (arow & 3)) * 8);

        float4 a0 = {0,0,0,0}, a1 = {0,0,0,0};
        if (isx) { a0 = *(const float4*)xrow; a1 = *(const float4*)(xrow + 4); }
        float4 w0 = *(const float4*)wrow, w1v = *(const float4*)(wrow + 4),
               w2v = *(const float4*)(wrow + 8), w3v = *(const float4*)(wrow + 12);

        f32x4 acc[4] = {};
        for (int k0 = 0; k0 < D_; k0 += 32) {
            int kn = (k0 + 32) & (D_ - 1);
            float4 na0 = {0,0,0,0}, na1 = {0,0,0,0};
            if (isx) { na0 = *(const float4*)(xrow + kn); na1 = *(const float4*)(xrow + kn + 4); }
            float4 nw0 = *(const float4*)(wrow + kn), nw1 = *(const float4*)(wrow + kn + 4),
                   nw2 = *(const float4*)(wrow + kn + 8), nw3 = *(const float4*)(wrow + kn + 12);
            __syncthreads();                         // prev iter's LDS reads done
            if (isx) *(bf16x8*)awr = cvt8(a0, a1);
            *(bf16x8*)bwr0 = cvt8(w0, w1v);
            *(bf16x8*)bwr1 = cvt8(w2v, w3v);
            if (valid) {
                float2* xo = (float2*)(xcopy + k0);
                xo[0] = make_float2(a0.x, a0.y); xo[1] = make_float2(a0.z, a0.w);
                xo[2] = make_float2(a1.x, a1.y); xo[3] = make_float2(a1.z, a1.w);
                xsq += a0.x*a0.x + a0.y*a0.y + a0.z*a0.z + a0.w*a0.w
                     + a1.x*a1.x + a1.y*a1.y + a1.z*a1.z + a1.w*a1.w;
            }
            __syncthreads();
            bf16x8 af = *(const bf16x8*)ard;
#pragma unroll
            for (int n = 0; n < 4; ++n) {
                int brow = cf * 64 + n * 16 + l15;
                bf16x8 bf = *(const bf16x8*)(Bs + brow * 32 + ((kg ^ (brow & 3)) * 8));
                acc[n] = __builtin_amdgcn_mfma_f32_16x16x32_bf16(af, bf, acc[n], 0, 0, 0);
            }
            a0 = na0; a1 = na1; w0 = nw0; w1v = nw1; w2v = nw2; w3v = nw3;
        }

        // h + b1 -> Hs (swizzled, bf16; single rounding)
#pragma unroll
        for (int n = 0; n < 4; ++n) {
            int j = cf * 64 + n * 16 + l15;
            float bias = b1[cond * H_ + j];
            int slot = j >> 3, elem = j & 7;
#pragma unroll
            for (int v = 0; v < 4; ++v) {
                int r = rf * 16 + kg * 4 + v;
                __bf16 hv = (__bf16)(acc[n][v] + bias);
                Hs[r * 128 + ((slot ^ (r & 15)) * 8) + elem] =
                    __builtin_bit_cast(unsigned short, hv);
            }
        }
        __syncthreads();

        // layer-2 A-fragments (rows of h) into registers
        bf16x8 pa[4];
        int hr = rf * 16 + l15;
#pragma unroll
        for (int ks = 0; ks < 4; ++ks)
            pa[ks] = *(const bf16x8*)(Hs + hr * 128 + (((ks * 4 + kg) ^ l15) * 8));

        int bbs[4];
#pragma unroll
        for (int v = 0; v < 4; ++v) {
            int pr = row0 + rf * 16 + kg * 4 + v;
            bbs[v] = (pr < end) ? sidx[pr] : -1;
        }
        float sq[4] = {0.f, 0.f, 0.f, 0.f};

        // ======== layer 2: out = h @ W2^T, 16 chunks x 64 cols, pipelined ========
        int cw = tid >> 2, q = tid & 3;
        const float* src0 = W2 + ((size_t)cond * D_ + cw) * H_ + q * 32;
        float4 fr[8];
#pragma unroll
        for (int s = 0; s < 4; ++s) {
            fr[2*s]   = *(const float4*)(src0 + s * 8);
            fr[2*s+1] = *(const float4*)(src0 + s * 8 + 4);
        }
        for (int ch = 0; ch < 16; ++ch) {
            const float* nsrc = src0 + (size_t)((ch + 1) & 15) * (64 * H_);
            float4 nfr[8];
#pragma unroll
            for (int s = 0; s < 4; ++s) {
                nfr[2*s]   = *(const float4*)(nsrc + s * 8);
                nfr[2*s+1] = *(const float4*)(nsrc + s * 8 + 4);
            }
            __syncthreads();                         // prev chunk's Ws reads done
#pragma unroll
            for (int s = 0; s < 4; ++s)
                *(bf16x8*)(Ws + cw * 128 + (((q * 4 + s) ^ (cw & 15)) * 8)) =
                    cvt8(fr[2*s], fr[2*s+1]);
            __syncthreads();
            f32x4 a2[2] = {};
#pragma unroll
            for (int ks = 0; ks < 4; ++ks) {
#pragma unroll
                for (int n = 0; n < 2; ++n) {
                    int wr = cf * 32 + n * 16 + l15;
                    bf16x8 bf = *(const bf16x8*)(Ws + wr * 128 + (((ks * 4 + kg) ^ (wr & 15)) * 8));
                    a2[n] = __builtin_amdgcn_mfma_f32_16x16x32_bf16(pa[ks], bf, a2[n], 0, 0, 0);
                }
            }
#pragma unroll
            for (int n = 0; n < 2; ++n) {
                int jg = ch * 64 + cf * 32 + n * 16 + l15;
                float bias = b2[cond * D_ + jg];
#pragma unroll
                for (int v = 0; v < 4; ++v) {
                    float val = a2[n][v] + bias;
                    if (bbs[v] >= 0) out[(size_t)bbs[v] * D_ + jg] = val;
                    sq[v] += val * val;
                }
            }
#pragma unroll
            for (int s = 0; s < 8; ++s) fr[s] = nfr[s];
        }
        // per-row sumsq partial: this wave covered 32 of 1024 cols in each chunk
#pragma unroll
        for (int v = 0; v < 4; ++v) {
            float s = sq[v];
            s += __shfl_xor(s, 1); s += __shfl_xor(s, 2);
            s += __shfl_xor(s, 4); s += __shfl_xor(s, 8);
            if (l15 == 0 && bbs[v] >= 0) psum[bbs[v] * 2 + cf] = s;   // written exactly once
        }
    }

    // ||x||^2 block reduction -> 16 buckets
    float s = xsq;
    s += __shfl_xor(s, 1);  s += __shfl_xor(s, 2);  s += __shfl_xor(s, 4);
    s += __shfl_xor(s, 8);  s += __shfl_xor(s, 16); s += __shfl_xor(s, 32);
    if (lane == 0) red[wv] = s;
    __syncthreads();
    if (tid == 0) atomicAdd(&ep[blockIdx.x & 15], red[0] + red[1] + red[2] + red[3]);
}

// ---- normalize masked rows (4 rows per block, no atomics) ----
__global__ __launch_bounds__(256) void k_norm(const float* __restrict__ psum,
                                              float* __restrict__ out) {
    int row = blockIdx.x * 4 + (threadIdx.x >> 6);
    int lane = threadIdx.x & 63;
    float s = psum[row * 2] + psum[row * 2 + 1];
    float inv = 1.0f / (sqrtf(s) + 1e-10f);
    float4* po = (float4*)out + (size_t)row * 256 + lane;
#pragma unroll
    for (int i = 0; i < 4; ++i) {
        float4 v = po[i * 64];
        v.x *= inv; v.y *= inv; v.z *= inv; v.w *= inv;
        po[i * 64] = v;
    }
}

__global__ void k_fin(const float* __restrict__ ep, float* __restrict__ out) {
    float s = 0.0f;
#pragma unroll
    for (int i = 0; i < 16; ++i) s += ep[i];
    out[BD] = 0.0f;
    out[BD + 1] = sqrtf(s);
}

extern "C" void kernel_launch(void* const* d_in, const int* in_sizes, int n_in,
                              void* d_out, int out_size, void* d_ws, size_t ws_size,
                              hipStream_t stream) {
    const float* x  = (const float*)d_in[0];
    const int*   c  = (const int*)d_in[1];
    const float* W1 = (const float*)d_in[2];
    const float* b1 = (const float*)d_in[3];
    const float* W2 = (const float*)d_in[4];
    const float* b2 = (const float*)d_in[5];
    float* out = (float*)d_out;
    char* ws = (char*)d_ws;
    int* wsi  = (int*)ws;
    float* psum = (float*)(ws + 65536);
    float* ep   = (float*)(ws + 131072);

    k_sort<<<1, 1024, 0, stream>>>(c, wsi, ep);
    k_f<<<8 * SLOTS, 256, 0, stream>>>(x, W1, b1, W2, b2, wsi, psum, out, ep);
    k_norm<<<B_ / 4, 256, 0, stream>>>(psum, out);
    k_fin<<<1, 1, 0, stream>>>(ep, out);
}

// Round 6
// 97.323 us; speedup vs baseline: 1.0822x; 1.0822x over previous
//
#include <hip/hip_runtime.h>
#include <hip/hip_bf16.h>
#include <math.h>

// B=8192, D=1024, H=128, C=16
// out tuple: masked[B*D], mask_norm(0.0), embed_norm(||x||F), x[B*D] -> f32
#define B_ 8192
#define D_ 1024
#define H_ 128
#define C_ 16
#define BD (B_*D_)
#define STM 16              // rows per subtile (one block per subtile)
#define SLOTS 64            // block slots per XCD; grid = 8*SLOTS = 512
#define MAXSUB 516          // worst-case subtiles per XCD

using bf16x8 = __attribute__((ext_vector_type(8))) __bf16;
using f32x4  = __attribute__((ext_vector_type(4))) float;
typedef unsigned short ushort_t;

// ws layout (bytes):
//   int idx 16      : nsub[8]
//   int idx 32      : subtbl[8][516][3] (cond,row0,end)  ends int 12416
//   int idx 16384   : sidx[8192]            (byte 65536)
//   262144          : ep[16] f32
//   524288          : w1s bf16 (4 MiB)  [cond][ks32][jf8][l15][kg][8]
//   4718592         : w2s bf16 (4 MiB)  [cond][ks4][jf64][l15][kg][8]
//   8912896         : xbf bf16 (16 MiB) [row][k]

__device__ inline bf16x8 cvt8(float4 a, float4 b) {
    bf16x8 r;
    r[0] = (__bf16)a.x; r[1] = (__bf16)a.y; r[2] = (__bf16)a.z; r[3] = (__bf16)a.w;
    r[4] = (__bf16)b.x; r[5] = (__bf16)b.y; r[6] = (__bf16)b.z; r[7] = (__bf16)b.w;
    return r;
}

// ---- histogram + per-XCD subtile table + scatter; zeroes ep ----
__global__ __launch_bounds__(1024) void k_sort(const int* __restrict__ c,
                                               int* __restrict__ w,
                                               float* __restrict__ ep) {
    __shared__ int hist[C_], base[C_];
    int tid = threadIdx.x;
    if (tid < C_) { hist[tid] = 0; ep[tid] = 0.0f; }
    __syncthreads();
    int myc[8];
#pragma unroll
    for (int i = 0; i < 8; ++i) {
        myc[i] = c[tid * 8 + i];
        atomicAdd(&hist[myc[i]], 1);
    }
    __syncthreads();
    if (tid == 0) {
        int off = 0; int ns[8] = {0,0,0,0,0,0,0,0};
        for (int cc = 0; cc < C_; ++cc) {
            int cnt = hist[cc]; base[cc] = off;
            int xcd = cc >> 1;                   // 2 conds/XCD -> 1MB bf16 weights in its L2
            for (int t = 0; t < cnt; t += STM) {
                int s = ns[xcd]++;
                int* e = &w[32 + (xcd * MAXSUB + s) * 3];
                e[0] = cc; e[1] = off + t; e[2] = off + cnt;
            }
            off += cnt;
        }
        for (int xx = 0; xx < 8; ++xx) w[16 + xx] = ns[xx];
    }
    __syncthreads();
#pragma unroll
    for (int i = 0; i < 8; ++i) {
        int pos = atomicAdd(&base[myc[i]], 1);
        w[16384 + pos] = tid * 8 + i;
    }
}

// ---- prep: x->bf16 + x copy + ||x||^2 ; W1,W2 -> bf16 in fragment order ----
__global__ __launch_bounds__(256) void k_prep(const float* __restrict__ x,
                                              const float* __restrict__ W1f,
                                              const float* __restrict__ W2f,
                                              float* __restrict__ out,
                                              __bf16* __restrict__ xbf,
                                              __bf16* __restrict__ w1s,
                                              __bf16* __restrict__ w2s,
                                              float* __restrict__ ep) {
    int bid = blockIdx.x, tid = threadIdx.x;
    if (bid < 1024) {                       // x: 8M floats, 2M float4, 2048/block
        float xsq = 0.0f;
        const float4* xv = (const float4*)x;
        float2* xo = (float2*)(out + (size_t)BD + 2);
#pragma unroll
        for (int u = 0; u < 4; ++u) {
            size_t i0 = (size_t)bid * 2048 + u * 512 + tid * 2;
            float4 p = xv[i0], q = xv[i0 + 1];
            xo[2*i0]   = make_float2(p.x, p.y); xo[2*i0+1] = make_float2(p.z, p.w);
            xo[2*i0+2] = make_float2(q.x, q.y); xo[2*i0+3] = make_float2(q.z, q.w);
            *(bf16x8*)(xbf + i0 * 4) = cvt8(p, q);
            xsq += p.x*p.x + p.y*p.y + p.z*p.z + p.w*p.w
                 + q.x*q.x + q.y*q.y + q.z*q.z + q.w*q.w;
        }
        float s = xsq;
        s += __shfl_xor(s, 1);  s += __shfl_xor(s, 2);  s += __shfl_xor(s, 4);
        s += __shfl_xor(s, 8);  s += __shfl_xor(s, 16); s += __shfl_xor(s, 32);
        __shared__ float red[4];
        int lane = tid & 63, wv = tid >> 6;
        if (lane == 0) red[wv] = s;
        __syncthreads();
        if (tid == 0) atomicAdd(&ep[bid & 15], red[0] + red[1] + red[2] + red[3]);
    } else if (bid < 1152) {                // W1 -> w1s: 262144 groups of 16B
        int wb = bid - 1024;
#pragma unroll
        for (int u = 0; u < 8; ++u) {
            int g = wb * 2048 + u * 256 + tid;
            int cond = g >> 14, rem = g & 16383;
            int ks = rem >> 9, rem2 = rem & 511;
            int jf = rem2 >> 6, lam = rem2 & 63;
            int l15 = lam >> 2, kg = lam & 3;
            const float* src = W1f + ((size_t)cond * 128 + jf * 16 + l15) * 1024 + ks * 32 + kg * 8;
            *(bf16x8*)(w1s + (size_t)g * 8) = cvt8(*(const float4*)src, *(const float4*)(src + 4));
        }
    } else {                                // W2 -> w2s: 262144 groups of 16B
        int wb = bid - 1152;
#pragma unroll
        for (int u = 0; u < 8; ++u) {
            int g = wb * 2048 + u * 256 + tid;
            int cond = g >> 14, rem = g & 16383;
            int ks = rem >> 12, rem2 = rem & 4095;
            int jf = rem2 >> 6, lam = rem2 & 63;
            int l15 = lam >> 2, kg = lam & 3;
            const float* src = W2f + ((size_t)cond * 1024 + jf * 16 + l15) * 128 + ks * 32 + kg * 8;
            *(bf16x8*)(w2s + (size_t)g * 8) = cvt8(*(const float4*)src, *(const float4*)(src + 4));
        }
    }
}

// ---- fused MLP: 16-row subtile per block; direct-global fragments; fused normalize ----
__global__ __launch_bounds__(256) void k_f(const __bf16* __restrict__ xbf,
                                           const __bf16* __restrict__ w1s,
                                           const __bf16* __restrict__ w2s,
                                           const float* __restrict__ b1f,
                                           const float* __restrict__ b2f,
                                           const int* __restrict__ wsi,
                                           float* __restrict__ out) {
    int xcd = blockIdx.x & 7, slot0 = blockIdx.x >> 3;
    int nsub = wsi[16 + xcd];
    const int* sidx = wsi + 16384;

    __shared__ ushort_t Hs[16 * 128];   // 4 KB  h tile (bf16, slot-XOR swizzled)
    __shared__ float Ot[16 * 1024];     // 64 KB out tile (chunk-XOR swizzled)
    __shared__ float sqs[64];           // per-row per-wave sumsq partials

    int tid = threadIdx.x;
    int wv = tid >> 6, lane = tid & 63, l15 = lane & 15, kg = lane >> 4;
    int cf = wv;                        // wave owns h-cols [cf*32,+32) and out-cols [cf*256,+256)
    int lofs = (l15 * 4 + kg) * 16;     // fragment-order lane offset (bytes)

    for (int si = slot0; si < nsub; si += SLOTS) {
        const int* e = wsi + 32 + (xcd * MAXSUB + si) * 3;
        int cond = e[0], row0 = e[1], end = e[2];
        int p = row0 + l15;
        int srow = sidx[p < end ? p : (end - 1)];

        // ===== L1: h[16][128], barrier-free K-loop, fragments direct from global =====
        const char* aAdr = (const char*)xbf + (size_t)srow * 2048 + kg * 16;
        const char* bAdr = (const char*)w1s + (size_t)cond * 262144 + cf * 2048 + lofs;
        f32x4 acc0 = {}, acc1 = {};
#pragma unroll 4
        for (int ks = 0; ks < 32; ++ks) {
            bf16x8 a  = *(const bf16x8*)(aAdr + ks * 64);
            bf16x8 b0 = *(const bf16x8*)(bAdr + ks * 8192);
            bf16x8 bb = *(const bf16x8*)(bAdr + ks * 8192 + 1024);
            acc0 = __builtin_amdgcn_mfma_f32_16x16x32_bf16(a, b0, acc0, 0, 0, 0);
            acc1 = __builtin_amdgcn_mfma_f32_16x16x32_bf16(a, bb, acc1, 0, 0, 0);
        }
        // h + b1 -> Hs (swizzled bf16)
        {
            int j0 = cf * 32 + l15;
            float bias0 = b1f[cond * 128 + j0];
            float bias1 = b1f[cond * 128 + j0 + 16];
            int sl0 = j0 >> 3, jb = j0 & 7;
#pragma unroll
            for (int v = 0; v < 4; ++v) {
                int r = kg * 4 + v;
                __bf16 h0 = (__bf16)(acc0[v] + bias0);
                __bf16 h1 = (__bf16)(acc1[v] + bias1);
                Hs[r * 128 + ((sl0 ^ (r & 7)) * 8) + jb]       = __builtin_bit_cast(ushort_t, h0);
                Hs[r * 128 + (((sl0 + 2) ^ (r & 7)) * 8) + jb] = __builtin_bit_cast(ushort_t, h1);
            }
        }
        __syncthreads();
        bf16x8 pa0 = *(const bf16x8*)(Hs + l15 * 128 + (((0 + kg) ^ (l15 & 7)) * 8));
        bf16x8 pa1 = *(const bf16x8*)(Hs + l15 * 128 + (((4 + kg) ^ (l15 & 7)) * 8));
        bf16x8 pa2 = *(const bf16x8*)(Hs + l15 * 128 + (((8 + kg) ^ (l15 & 7)) * 8));
        bf16x8 pa3 = *(const bf16x8*)(Hs + l15 * 128 + (((12 + kg) ^ (l15 & 7)) * 8));
        __syncthreads();   // protect Hs for next subtile

        // ===== L2: out[16][1024], barrier-free, W2 fragments direct from global =====
        const char* w2b = (const char*)w2s + (size_t)cond * 262144 + cf * 16384 + lofs;
        float sq0 = 0.f, sq1 = 0.f, sq2 = 0.f, sq3 = 0.f;
#pragma unroll 2
        for (int f = 0; f < 16; ++f) {
            bf16x8 q0 = *(const bf16x8*)(w2b + f * 1024);
            bf16x8 q1 = *(const bf16x8*)(w2b + f * 1024 + 65536);
            bf16x8 q2 = *(const bf16x8*)(w2b + f * 1024 + 131072);
            bf16x8 q3 = *(const bf16x8*)(w2b + f * 1024 + 196608);
            f32x4 a2 = {};
            a2 = __builtin_amdgcn_mfma_f32_16x16x32_bf16(pa0, q0, a2, 0, 0, 0);
            a2 = __builtin_amdgcn_mfma_f32_16x16x32_bf16(pa1, q1, a2, 0, 0, 0);
            a2 = __builtin_amdgcn_mfma_f32_16x16x32_bf16(pa2, q2, a2, 0, 0, 0);
            a2 = __builtin_amdgcn_mfma_f32_16x16x32_bf16(pa3, q3, a2, 0, 0, 0);
            int jg = cf * 256 + f * 16 + l15;
            float bias = b2f[cond * 1024 + jg];
            int chunk = jg >> 2, jb2 = jg & 3;
            float v0 = a2[0] + bias, v1 = a2[1] + bias, v2 = a2[2] + bias, v3 = a2[3] + bias;
            int r0 = kg * 4;
            Ot[(r0    ) * 1024 + ((chunk ^ ((r0    ) & 7)) * 4) + jb2] = v0;
            Ot[(r0 + 1) * 1024 + ((chunk ^ ((r0 + 1) & 7)) * 4) + jb2] = v1;
            Ot[(r0 + 2) * 1024 + ((chunk ^ ((r0 + 2) & 7)) * 4) + jb2] = v2;
            Ot[(r0 + 3) * 1024 + ((chunk ^ ((r0 + 3) & 7)) * 4) + jb2] = v3;
            sq0 += v0 * v0; sq1 += v1 * v1; sq2 += v2 * v2; sq3 += v3 * v3;
        }
        // per-row partial (this wave's 256 cols) -> sqs[r][cf]
        {
            float s0 = sq0, s1 = sq1, s2 = sq2, s3 = sq3;
            s0 += __shfl_xor(s0, 1); s0 += __shfl_xor(s0, 2); s0 += __shfl_xor(s0, 4); s0 += __shfl_xor(s0, 8);
            s1 += __shfl_xor(s1, 1); s1 += __shfl_xor(s1, 2); s1 += __shfl_xor(s1, 4); s1 += __shfl_xor(s1, 8);
            s2 += __shfl_xor(s2, 1); s2 += __shfl_xor(s2, 2); s2 += __shfl_xor(s2, 4); s2 += __shfl_xor(s2, 8);
            s3 += __shfl_xor(s3, 1); s3 += __shfl_xor(s3, 2); s3 += __shfl_xor(s3, 4); s3 += __shfl_xor(s3, 8);
            if (l15 == 0) {
                sqs[(kg * 4 + 0) * 4 + cf] = s0;
                sqs[(kg * 4 + 1) * 4 + cf] = s1;
                sqs[(kg * 4 + 2) * 4 + cf] = s2;
                sqs[(kg * 4 + 3) * 4 + cf] = s3;
            }
        }
        __syncthreads();
        // ===== fused normalize + coalesced float4 store =====
        {
            int r = tid >> 4, cb = tid & 15;
            float s = sqs[r * 4] + sqs[r * 4 + 1] + sqs[r * 4 + 2] + sqs[r * 4 + 3];
            float inv = 1.0f / (sqrtf(s) + 1e-10f);
            int pr = row0 + r;
            if (pr < end) {
                float4* go = (float4*)(out + (size_t)sidx[pr] * D_);
#pragma unroll
                for (int i = 0; i < 16; ++i) {
                    int chunk = cb + i * 16;
                    float4 vv = *(const float4*)(Ot + r * 1024 + ((chunk ^ (r & 7)) * 4));
                    vv.x *= inv; vv.y *= inv; vv.z *= inv; vv.w *= inv;
                    go[chunk] = vv;
                }
            }
        }
        __syncthreads();   // Ot/sqs reads done before next subtile overwrites
    }
}

__global__ void k_fin(const float* __restrict__ ep, float* __restrict__ out) {
    float s = 0.0f;
#pragma unroll
    for (int i = 0; i < 16; ++i) s += ep[i];
    out[BD] = 0.0f;
    out[BD + 1] = sqrtf(s);
}

extern "C" void kernel_launch(void* const* d_in, const int* in_sizes, int n_in,
                              void* d_out, int out_size, void* d_ws, size_t ws_size,
                              hipStream_t stream) {
    const float* x  = (const float*)d_in[0];
    const int*   c  = (const int*)d_in[1];
    const float* W1 = (const float*)d_in[2];
    const float* b1 = (const float*)d_in[3];
    const float* W2 = (const float*)d_in[4];
    const float* b2 = (const float*)d_in[5];
    float* out = (float*)d_out;
    char* ws = (char*)d_ws;
    int* wsi = (int*)ws;
    float* ep   = (float*)(ws + 262144);
    __bf16* w1s = (__bf16*)(ws + 524288);
    __bf16* w2s = (__bf16*)(ws + 4718592);
    __bf16* xbf = (__bf16*)(ws + 8912896);

    k_sort<<<1, 1024, 0, stream>>>(c, wsi, ep);
    k_prep<<<1280, 256, 0, stream>>>(x, W1, W2, out, xbf, w1s, w2s, ep);
    k_f<<<8 * SLOTS, 256, 0, stream>>>(xbf, w1s, w2s, b1, b2, wsi, out);
    k_fin<<<1, 1, 0, stream>>>(ep, out);
}